// Round 2
// baseline (96.271 us; speedup 1.0000x reference)
//
#include <hip/hip_runtime.h>
#include <math.h>

#define N 8192
#define D 3072

typedef float f4 __attribute__((ext_vector_type(4)));

// Kernel 1: one WAVE per row (4 rows per 256-thread block, no LDS, no barrier).
// Computes row sum S and dot(x[i,:], w) in one pass over x.
// Epilogue factorizes the kernel matrix: e[i] = exp(S), r[i] = exp(-S),
// so kmat needs no transcendentals. e is stored at ws+1 so that the
// float4 bulk of each K row (j = 3 mod 4) reads 16B-aligned.
__global__ __launch_bounds__(256) void rowsum_dot_kernel(
    const float* __restrict__ x, const float* __restrict__ w,
    float* __restrict__ ws_e /* ws[0..8192], e[i] at ws_e[1+i] */,
    float* __restrict__ r, float* __restrict__ pred) {
    const int wave = threadIdx.x >> 6;
    const int lane = threadIdx.x & 63;
    const int i = blockIdx.x * 4 + wave;
    const float* xrow = x + (size_t)i * D;

    float sum = 0.f, dot = 0.f;
    // 3072 floats / 64 lanes = 48 = 12 float4 per lane, coalesced 1KB/instr
    #pragma unroll
    for (int k = 0; k < 12; ++k) {
        const int idx = (k * 64 + lane) * 4;
        const f4 xv = __builtin_nontemporal_load(
            reinterpret_cast<const f4*>(xrow + idx));
        const f4 wv = *reinterpret_cast<const f4*>(w + idx);
        sum += (xv.x + xv.y) + (xv.z + xv.w);
        dot += xv.x * wv.x + xv.y * wv.y + xv.z * wv.z + xv.w * wv.w;
    }
    #pragma unroll
    for (int off = 32; off > 0; off >>= 1) {
        sum += __shfl_down(sum, off, 64);
        dot += __shfl_down(dot, off, 64);
    }
    if (lane == 0) {
        ws_e[1 + i] = __expf(sum);   // e[i]
        r[i]        = __expf(-sum);  // 1/e[i] (via exp, matches ref precision)
        pred[i]     = dot + w[D];    // + bias
    }
}

// Kernel 2: one block per row of K. K[i,j] = e[j] * r[i]  (== exp(s[j]-s[i])).
// K base is at float offset 8193 of d_out => row base ≡ 1 (mod 4 floats).
// Peel 3-head + 1-tail; bulk is aligned float4 nontemporal stores.
// e reads are L1-resident (32KB table); r[i] is wave-uniform (scalar load).
__global__ __launch_bounds__(256) void kmat_kernel(
    const float* __restrict__ ws_e, const float* __restrict__ r,
    float* __restrict__ K) {
    const int i = blockIdx.x;
    const int tid = threadIdx.x;
    const float ri = r[i];
    float* __restrict__ row = K + (size_t)i * N;
    const float* __restrict__ e = ws_e + 1;  // e[j] = ws_e[1+j]

    if (tid < 3) row[tid] = e[tid] * ri;
    if (tid == 3) row[N - 1] = e[N - 1] * ri;

    // bulk: j = 3 .. 8190, 2047 float4 chunks; e+j is 16B-aligned (ws_e+4+4v)
    #pragma unroll 2
    for (int v = tid; v < 2047; v += 256) {
        const int j = 3 + v * 4;
        const f4 ev = *reinterpret_cast<const f4*>(e + j);
        const f4 o = ev * ri;
        __builtin_nontemporal_store(o, reinterpret_cast<f4*>(row + j));
    }
}

// Kernel 3: single-block loss reduction.
// loss = 0.5*sqrt(sum((y - pred)^2))/N + sum(|w|)
__global__ __launch_bounds__(1024) void loss_kernel(
    const float* __restrict__ pred, const int* __restrict__ y,
    const float* __restrict__ w, float* __restrict__ loss_out) {
    const int tid = threadIdx.x;
    float acc = 0.f;
    for (int i = tid; i < N; i += 1024) {
        const float d = (float)y[i] - pred[i];
        acc += d * d;
    }
    float wacc = 0.f;
    for (int i = tid; i < D + 1; i += 1024) wacc += fabsf(w[i]);

    #pragma unroll
    for (int off = 32; off > 0; off >>= 1) {
        acc  += __shfl_down(acc, off, 64);
        wacc += __shfl_down(wacc, off, 64);
    }
    __shared__ float la[16], lw[16];
    const int wave = tid >> 6;
    if ((tid & 63) == 0) { la[wave] = acc; lw[wave] = wacc; }
    __syncthreads();
    if (tid == 0) {
        float a = 0.f, b = 0.f;
        #pragma unroll
        for (int k = 0; k < 16; ++k) { a += la[k]; b += lw[k]; }
        loss_out[0] = 0.5f * sqrtf(a) / (float)N + b;
    }
}

extern "C" void kernel_launch(void* const* d_in, const int* in_sizes, int n_in,
                              void* d_out, int out_size, void* d_ws, size_t ws_size,
                              hipStream_t stream) {
    const float* x = (const float*)d_in[0];   // [8192, 3072] f32
    const int*   y = (const int*)d_in[1];     // [8192, 1] i32
    const float* w = (const float*)d_in[2];   // [3073, 1] f32

    float* out  = (float*)d_out;
    float* pred = out;              // [8192]
    float* loss = out + N;          // [1]
    float* K    = out + N + 1;      // [8192, 8192]

    float* ws_e = (float*)d_ws;     // [8193]: e[i] at ws_e[1+i]
    float* r    = ws_e + 8200;      // [8192] (8-float aligned)

    rowsum_dot_kernel<<<N / 4, 256, 0, stream>>>(x, w, ws_e, r, pred);
    kmat_kernel<<<N, 256, 0, stream>>>(ws_e, r, K);
    loss_kernel<<<1, 1024, 0, stream>>>(pred, y, w, loss);
}

// Round 3
// 90.216 us; speedup vs baseline: 1.0671x; 1.0671x over previous
//
#include <hip/hip_runtime.h>
#include <math.h>

#define N 8192
#define D 3072

typedef float f4 __attribute__((ext_vector_type(4)));

// Kernel 1: one WAVE per row (4 rows per 256-thread block, no LDS, no barrier).
// Computes row sum S and dot(x[i,:], w) in one pass over x.
// Epilogue factorizes the kernel matrix: e[i] = exp(S), r[i] = exp(-S),
// so kmat needs no transcendentals. e is stored at ws+1 so that the
// float4 bulk of each K row (j = 3 mod 4) reads 16B-aligned.
__global__ __launch_bounds__(256) void rowsum_dot_kernel(
    const float* __restrict__ x, const float* __restrict__ w,
    float* __restrict__ ws_e /* e[i] at ws_e[1+i] */,
    float* __restrict__ r, float* __restrict__ pred) {
    const int wave = threadIdx.x >> 6;
    const int lane = threadIdx.x & 63;
    const int i = blockIdx.x * 4 + wave;
    const float* xrow = x + (size_t)i * D;

    float sum = 0.f, dot = 0.f;
    // 3072 floats / 64 lanes = 48 = 12 float4 per lane, coalesced 1KB/instr
    #pragma unroll
    for (int k = 0; k < 12; ++k) {
        const int idx = (k * 64 + lane) * 4;
        const f4 xv = *reinterpret_cast<const f4*>(xrow + idx);
        const f4 wv = *reinterpret_cast<const f4*>(w + idx);
        sum += (xv.x + xv.y) + (xv.z + xv.w);
        dot += xv.x * wv.x + xv.y * wv.y + xv.z * wv.z + xv.w * wv.w;
    }
    #pragma unroll
    for (int off = 32; off > 0; off >>= 1) {
        sum += __shfl_down(sum, off, 64);
        dot += __shfl_down(dot, off, 64);
    }
    if (lane == 0) {
        ws_e[1 + i] = __expf(sum);   // e[i]
        r[i]        = __expf(-sum);  // 1/e[i]
        pred[i]     = dot + w[D];    // + bias
    }
}

// Kernel 2: one block per row of K. K[i,j] = e[j] * r[i]  (== exp(s[j]-s[i])).
// K base is at float offset 8193 of d_out => row base ≡ 1 (mod 4 floats).
// Peel 3-head + 1-tail; bulk is plain aligned float4 stores (nt hurt in R2).
__global__ __launch_bounds__(256) void kmat_kernel(
    const float* __restrict__ ws_e, const float* __restrict__ r,
    float* __restrict__ K) {
    const int i = blockIdx.x;
    const int tid = threadIdx.x;
    const float ri = r[i];
    float* __restrict__ row = K + (size_t)i * N;
    const float* __restrict__ e = ws_e + 1;  // e[j] = ws_e[1+j]

    if (tid < 3) row[tid] = e[tid] * ri;
    if (tid == 3) row[N - 1] = e[N - 1] * ri;

    // bulk: j = 3 .. 8190, 2047 float4 chunks; e+j is 16B-aligned
    for (int v = tid; v < 2047; v += 256) {
        const int j = 3 + v * 4;
        const f4 ev = *reinterpret_cast<const f4*>(e + j);
        const f4 o = ev * ri;
        *reinterpret_cast<f4*>(row + j) = o;
    }
}

// Kernel 3: single-block loss reduction.
// loss = 0.5*sqrt(sum((y - pred)^2))/N + sum(|w|)
__global__ __launch_bounds__(1024) void loss_kernel(
    const float* __restrict__ pred, const int* __restrict__ y,
    const float* __restrict__ w, float* __restrict__ loss_out) {
    const int tid = threadIdx.x;
    float acc = 0.f;
    for (int i = tid; i < N; i += 1024) {
        const float d = (float)y[i] - pred[i];
        acc += d * d;
    }
    float wacc = 0.f;
    for (int i = tid; i < D + 1; i += 1024) wacc += fabsf(w[i]);

    #pragma unroll
    for (int off = 32; off > 0; off >>= 1) {
        acc  += __shfl_down(acc, off, 64);
        wacc += __shfl_down(wacc, off, 64);
    }
    __shared__ float la[16], lw[16];
    const int wave = tid >> 6;
    if ((tid & 63) == 0) { la[wave] = acc; lw[wave] = wacc; }
    __syncthreads();
    if (tid == 0) {
        float a = 0.f, b = 0.f;
        #pragma unroll
        for (int k = 0; k < 16; ++k) { a += la[k]; b += lw[k]; }
        loss_out[0] = 0.5f * sqrtf(a) / (float)N + b;
    }
}

extern "C" void kernel_launch(void* const* d_in, const int* in_sizes, int n_in,
                              void* d_out, int out_size, void* d_ws, size_t ws_size,
                              hipStream_t stream) {
    const float* x = (const float*)d_in[0];   // [8192, 3072] f32
    const int*   y = (const int*)d_in[1];     // [8192, 1] i32
    const float* w = (const float*)d_in[2];   // [3073, 1] f32

    float* out  = (float*)d_out;
    float* pred = out;              // [8192]
    float* loss = out + N;          // [1]
    float* K    = out + N + 1;      // [8192, 8192]

    float* ws_e = (float*)d_ws;     // e[i] at ws_e[1+i]
    float* r    = ws_e + 8200;      // [8192] (32B aligned)

    rowsum_dot_kernel<<<N / 4, 256, 0, stream>>>(x, w, ws_e, r, pred);
    kmat_kernel<<<N, 256, 0, stream>>>(ws_e, r, K);
    loss_kernel<<<1, 1024, 0, stream>>>(pred, y, w, loss);
}